// Round 5
// baseline (9454.700 us; speedup 1.0000x reference)
//
#include <hip/hip_runtime.h>
#include <math.h>

typedef unsigned short u16;
typedef unsigned int u32;

// ---------- bf16 helpers (for LDS/ws intermediates only; I/O is f32) ----------
__device__ __forceinline__ float b2f(u16 u) {
    union { u32 ui; float f; } v; v.ui = ((u32)u) << 16; return v.f;
}
__device__ __forceinline__ u16 f2b(float f) {
    union { float f; u32 ui; } v; v.f = f;
    u32 x = v.ui;
    u32 r = (x + 0x7fffu + ((x >> 16) & 1u)) >> 16;
    return (u16)r;
}
__device__ __forceinline__ float lo16(u32 u) { union { u32 i; float f; } v; v.i = u << 16; return v.f; }
__device__ __forceinline__ float hi16(u32 u) { union { u32 i; float f; } v; v.i = u & 0xffff0000u; return v.f; }
__device__ __forceinline__ float sigf(float x) { return 1.0f / (1.0f + expf(-x)); }

// ---------- problem constants ----------
#define GNODES 128
#define EMBD   256
#define NB     64
#define TS     32
#define GOA    268
#define GLO    524

// output layout (f32 elements)
#define OUT_SPATIAL 0
#define OUT_NS      524288
#define OUT_V       524800
#define OUT_H       524864

// workspace byte offsets — total ~16.2 MB
#define WS_GOA   ((size_t)0)
#define WS_HBUF  ((size_t)2195456)
#define WS_CBUF  ((size_t)2260992)
#define WS_HOUT  ((size_t)2326528)
#define WS_GLO   ((size_t)2392064)
#define WS_WIHT  ((size_t)2526208)
#define WS_WHHT  ((size_t)3574784)
#define WS_BSUM  ((size_t)4623360)
#define WS_C2    ((size_t)4627456)
#define WS_C3    ((size_t)4889600)
#define WS_C4    ((size_t)5413888)
#define WS_C5    ((size_t)7511040)
#define WS_SL    ((size_t)15899648)

// ======================================================================
// GCN: one block per (n,t). 512 threads. Activations bf16 in LDS.
// ======================================================================
__global__ __launch_bounds__(512) void gcn_kernel(
    const float* __restrict__ G, const float* __restrict__ X, const float* __restrict__ pa,
    const float* __restrict__ We, const float* __restrict__ be,
    const float* __restrict__ W1, const float* __restrict__ b1,
    const float* __restrict__ W2, const float* __restrict__ b2,
    const float* __restrict__ W3, const float* __restrict__ b3,
    float* __restrict__ goaAll)
{
    __shared__ u16 Sa[GNODES * EMBD];
    __shared__ u16 Sb[GNODES * EMBD];
    __shared__ float dis[GNODES];

    const int item = blockIdx.x;
    const int tid  = threadIdx.x;
    const int j    = tid & 255;
    const int hi   = tid >> 8;
    const float* Gp = G + (size_t)item * GNODES * GNODES;
    const float* Xp = X + (size_t)item * GNODES * 64;

    for (int idx = tid; idx < GNODES * 64; idx += 512) Sb[idx] = f2b(Xp[idx]);

    if (tid < GNODES) {
        const float4* gr = (const float4*)(Gp + tid * GNODES);
        float s = 0.f;
        for (int k = 0; k < 32; ++k) { float4 g = gr[k]; s += g.x + g.y + g.z + g.w; }
        dis[tid] = 1.0f / sqrtf(s + 1.0f);
    }
    __syncthreads();

    {
        float bj = be[j];
        for (int i = hi * 64; i < hi * 64 + 64; ++i) {
            float acc = bj;
            const u32* xr = (const u32*)(Sb + i * 64);
            for (int kc = 0; kc < 32; ++kc) {
                u32 p = xr[kc];
                int k = kc * 2;
                acc = fmaf(lo16(p), We[k * EMBD + j], acc);
                acc = fmaf(hi16(p), We[(k + 1) * EMBD + j], acc);
            }
            Sa[i * EMBD + j] = f2b(tanhf(acc));
        }
    }
    __syncthreads();

    for (int l = 0; l < 3; ++l) {
        const float* W = (l == 0) ? W1 : ((l == 1) ? W2 : W3);
        const float bj = ((l == 0) ? b1 : ((l == 1) ? b2 : b3))[j];

        for (int i0 = hi * 64; i0 < hi * 64 + 64; i0 += 16) {
            float acc[16];
#pragma unroll
            for (int r = 0; r < 16; ++r) acc[r] = bj;
            for (int k = 0; k < EMBD; k += 8) {
                float w[8];
#pragma unroll
                for (int q = 0; q < 8; ++q) w[q] = W[(k + q) * EMBD + j];
#pragma unroll
                for (int r = 0; r < 16; ++r) {
                    uint4 p = *(const uint4*)&Sa[(i0 + r) * EMBD + k];
                    acc[r] = fmaf(lo16(p.x), w[0], acc[r]);
                    acc[r] = fmaf(hi16(p.x), w[1], acc[r]);
                    acc[r] = fmaf(lo16(p.y), w[2], acc[r]);
                    acc[r] = fmaf(hi16(p.y), w[3], acc[r]);
                    acc[r] = fmaf(lo16(p.z), w[4], acc[r]);
                    acc[r] = fmaf(hi16(p.z), w[5], acc[r]);
                    acc[r] = fmaf(lo16(p.w), w[6], acc[r]);
                    acc[r] = fmaf(hi16(p.w), w[7], acc[r]);
                }
            }
#pragma unroll
            for (int r = 0; r < 16; ++r) Sb[(i0 + r) * EMBD + j] = f2b(acc[r]);
        }
        __syncthreads();

        for (int i0 = hi * 64; i0 < hi * 64 + 64; i0 += 8) {
            float acc[8];
#pragma unroll
            for (int r = 0; r < 8; ++r) acc[r] = 0.f;
            for (int k = 0; k < GNODES; k += 4) {
                float tv0 = b2f(Sb[(k + 0) * EMBD + j]) * dis[k + 0];
                float tv1 = b2f(Sb[(k + 1) * EMBD + j]) * dis[k + 1];
                float tv2 = b2f(Sb[(k + 2) * EMBD + j]) * dis[k + 2];
                float tv3 = b2f(Sb[(k + 3) * EMBD + j]) * dis[k + 3];
#pragma unroll
                for (int r = 0; r < 8; ++r) {
                    float4 g = *(const float4*)&Gp[(i0 + r) * GNODES + k];
                    acc[r] = fmaf(g.x, tv0, acc[r]);
                    acc[r] = fmaf(g.y, tv1, acc[r]);
                    acc[r] = fmaf(g.z, tv2, acc[r]);
                    acc[r] = fmaf(g.w, tv3, acc[r]);
                }
            }
#pragma unroll
            for (int r = 0; r < 8; ++r) {
                float di = dis[i0 + r];
                float selfv = di * b2f(Sb[(i0 + r) * EMBD + j]);
                Sa[(i0 + r) * EMBD + j] = f2b(tanhf(di * (acc[r] + selfv)));
            }
        }
        __syncthreads();
    }

    const int n = item >> 5, t = item & 31;
    float* gdst = goaAll + ((size_t)t * NB + n) * GOA;
    if (tid < 256) {
        float m = -2.0f;
        for (int i = 0; i < GNODES; ++i) m = fmaxf(m, b2f(Sa[i * EMBD + tid]));
        gdst[tid] = m;
    } else if (tid < 256 + 12) {
        gdst[256 + (tid - 256)] = pa[(size_t)item * 12 + (tid - 256)];
    }
}

// ======================================================================
__global__ void wtrans(const float* __restrict__ Wih, const float* __restrict__ Whh,
                       const float* __restrict__ bih, const float* __restrict__ bhh,
                       float* __restrict__ wihT, float* __restrict__ whhT, float* __restrict__ bsum)
{
    int idx = blockIdx.x * 256 + threadIdx.x;
    int r = idx >> 8;
    int k = idx & 255;
    wihT[k * 1024 + r] = Wih[idx];
    whhT[k * 1024 + r] = Whh[idx];
    if (idx < 1024) bsum[idx] = bih[idx] + bhh[idx];
}

// ======================================================================
__global__ __launch_bounds__(256) void lstm_all(
    const float* __restrict__ goaAll, const float* __restrict__ Wle, const float* __restrict__ ble,
    const float* __restrict__ wihT, const float* __restrict__ whhT, const float* __restrict__ bsum,
    const int* __restrict__ relf, const float* __restrict__ lh,
    float* __restrict__ hbuf, float* __restrict__ cbuf, float* __restrict__ hout)
{
    __shared__ float gl[GOA];
    __shared__ float xv[256];
    __shared__ float hv[256];
    const int n = blockIdx.x, u = threadIdx.x;

    hv[u] = lh[n * 256 + u];
    float cpriv = lh[16384 + n * 256 + u];
    const float blev = ble[u];
    const float bs0 = bsum[u], bs1 = bsum[256 + u], bs2 = bsum[512 + u], bs3 = bsum[768 + u];

    for (int t = 0; t < TS; ++t) {
        const float* gsrc = goaAll + ((size_t)t * NB + n) * GOA;
        gl[u] = gsrc[u];
        if (u < 12) gl[256 + u] = gsrc[256 + u];
        __syncthreads();

        float acc = blev;
        for (int k = 0; k < GOA; ++k) acc = fmaf(gl[k], Wle[k * 256 + u], acc);
        xv[u] = tanhf(acc);
        __syncthreads();

        float a0 = bs0, a1 = bs1, a2 = bs2, a3 = bs3;
        for (int k = 0; k < 256; ++k) {
            float xk = xv[k], hk = hv[k];
            const float* wi = wihT + k * 1024 + u;
            const float* wh = whhT + k * 1024 + u;
            a0 = fmaf(xk, wi[0],   fmaf(hk, wh[0],   a0));
            a1 = fmaf(xk, wi[256], fmaf(hk, wh[256], a1));
            a2 = fmaf(xk, wi[512], fmaf(hk, wh[512], a2));
            a3 = fmaf(xk, wi[768], fmaf(hk, wh[768], a3));
        }
        float cn = sigf(a1) * cpriv + sigf(a0) * tanhf(a2);
        float hn = sigf(a3) * tanhf(cn);
        float kp = (relf[n * TS + t] != 0) ? 1.f : 0.f;
        if (t == TS - 1) {
            hout[n * 256 + u] = hn;
            hbuf[n * 256 + u] = hn * kp;
            cbuf[n * 256 + u] = cn * kp;
        }
        cpriv = cn * kp;
        __syncthreads();
        hv[u] = hn * kp;
        __syncthreads();
    }
}

// ======================================================================
// heads — OUTPUTS ARE FLOAT32
// ======================================================================
__global__ __launch_bounds__(256) void heads(
    const float* __restrict__ goaAll, const float* __restrict__ hout,
    const float* __restrict__ hbuf, const float* __restrict__ cbuf,
    const float* __restrict__ Wa, const float* __restrict__ ba,
    const float* __restrict__ Wv, const float* __restrict__ bv,
    const int* __restrict__ avail, float* __restrict__ glo, float* __restrict__ out)
{
    __shared__ float gl[GLO];
    __shared__ float lg[8];
    const int n = blockIdx.x, tid = threadIdx.x;
    const float* gsrc = goaAll + ((size_t)31 * NB + n) * GOA;
    gl[tid] = hout[n * 256 + tid];
    gl[256 + tid] = gsrc[tid];
    if (tid < 12) gl[512 + tid] = gsrc[256 + tid];
    __syncthreads();

    glo[n * GLO + tid]       = gl[tid];
    glo[n * GLO + 256 + tid] = gl[256 + tid];
    if (tid < 12) glo[n * GLO + 512 + tid] = gl[512 + tid];

    out[OUT_H + n * 256 + tid]         = hbuf[n * 256 + tid];
    out[OUT_H + 16384 + n * 256 + tid] = cbuf[n * 256 + tid];

    if (tid < 8) {
        float a = ba[tid];
        for (int k = 0; k < GLO; ++k) a = fmaf(gl[k], Wa[k * 8 + tid], a);
        lg[tid] = (avail[n * 8 + tid] == 0) ? -INFINITY : a;
    } else if (tid == 8) {
        float a = bv[0];
        for (int k = 0; k < GLO; ++k) a = fmaf(gl[k], Wv[k], a);
        out[OUT_V + n] = a;
    }
    __syncthreads();
    if (tid == 0) {
        float m = -INFINITY;
        for (int a = 0; a < 8; ++a) m = fmaxf(m, lg[a]);
        float e[8], s = 0.f;
        for (int a = 0; a < 8; ++a) { e[a] = expf(lg[a] - m); s += e[a]; }
        float inv = 1.f / s;
        for (int a = 0; a < 8; ++a) out[OUT_NS + n * 8 + a] = e[a] * inv;
    }
}

// ======================================================================
__global__ __launch_bounds__(256) void dec12(
    const float* __restrict__ glo, const float* __restrict__ Wt1, const float* __restrict__ bt1,
    const float* __restrict__ Wc2, const float* __restrict__ bc2, u16* __restrict__ c2)
{
    __shared__ float gl[GLO];
    __shared__ float s1[4096];
    const int n = blockIdx.x, tid = threadIdx.x;
    gl[tid] = glo[n * GLO + tid];
    gl[256 + tid] = glo[n * GLO + 256 + tid];
    if (tid < 12) gl[512 + tid] = glo[n * GLO + 512 + tid];
    __syncthreads();

    {
        const int f = tid;
        float acc[16];
        float bb = bt1[f];
#pragma unroll
        for (int p = 0; p < 16; ++p) acc[p] = bb;
        for (int c = 0; c < GLO; ++c) {
            float g = gl[c];
            const float* wp = Wt1 + ((size_t)c * 256 + f) * 16;
#pragma unroll
            for (int p = 0; p < 16; ++p) acc[p] = fmaf(g, wp[p], acc[p]);
        }
#pragma unroll
        for (int p = 0; p < 16; ++p) {
            float v = acc[p];
            s1[f * 16 + p] = v > 0.f ? v : 0.1f * v;
        }
    }
    __syncthreads();

    for (int u = tid; u < 2048; u += 256) {
        int p = u & 15; int x = p & 3; int y = p >> 2;
        int co = u >> 4;
        float acc = bc2[co];
        const float* wp = Wc2 + (size_t)co * 256 * 9;
        for (int ci = 0; ci < 256; ++ci) {
            const float* wc = wp + ci * 9;
            const float* sc = s1 + ci * 16;
#pragma unroll
            for (int ky = 0; ky < 3; ++ky) {
                int yy = y + ky - 1;
                if (yy < 0 || yy > 3) continue;
#pragma unroll
                for (int kx = 0; kx < 3; ++kx) {
                    int xx = x + kx - 1;
                    if (xx < 0 || xx > 3) continue;
                    acc = fmaf(sc[yy * 4 + xx], wc[ky * 3 + kx], acc);
                }
            }
        }
        c2[(size_t)(n * 128 + co) * 16 + p] = f2b(acc);
    }
}

// ======================================================================
__global__ __launch_bounds__(256) void up_conv(
    const u16* __restrict__ in, const float* __restrict__ w, const float* __restrict__ bias,
    u16* __restrict__ out, int CIN, int CO, int H, int W, int coTiles)
{
    __shared__ u16 S[65536];
    const int tid = threadIdx.x;
    const int n  = blockIdx.x / coTiles;
    const int ct = blockIdx.x % coTiles;
    const int H2 = 2 * H, W2 = 2 * W;
    const u16* ip = in + (size_t)n * CIN * H * W;

    const int tot = CIN * H2 * W2;
    for (int i = tid; i < tot; i += 256) {
        int x2 = i % W2; int y2 = (i / W2) % H2; int ci = i / (W2 * H2);
        int y0 = (y2 - 1) >> 1; float fy = (y2 & 1) ? 0.25f : 0.75f;
        int x0 = (x2 - 1) >> 1; float fx = (x2 & 1) ? 0.25f : 0.75f;
        int y0c = y0 < 0 ? 0 : y0, y1c = y0 + 1 > H - 1 ? H - 1 : y0 + 1;
        int x0c = x0 < 0 ? 0 : x0, x1c = x0 + 1 > W - 1 ? W - 1 : x0 + 1;
        const u16* b = ip + ci * H * W;
        float v00 = b2f(b[y0c * W + x0c]), v01 = b2f(b[y0c * W + x1c]);
        float v10 = b2f(b[y1c * W + x0c]), v11 = b2f(b[y1c * W + x1c]);
        float v = (1.f - fy) * ((1.f - fx) * v00 + fx * v01)
                +        fy  * ((1.f - fx) * v10 + fx * v11);
        S[i] = f2b(fmaxf(v, 0.f));
    }
    __syncthreads();

    const int xg = W2 >> 3;
    const int units = 4 * H2 * xg;
    for (int ugl = tid; ugl < units; ugl += 256) {
        int x0p = (ugl % xg) * 8;
        int y   = (ugl / xg) % H2;
        int cp  = ugl / (xg * H2);
        int co0 = ct * 8 + cp * 2;
        float acc0[8], acc1[8];
        float bb0 = bias[co0], bb1 = bias[co0 + 1];
#pragma unroll
        for (int d = 0; d < 8; ++d) { acc0[d] = bb0; acc1[d] = bb1; }
        const float* w0 = w + (size_t)co0 * CIN * 9;
        const float* w1 = w0 + (size_t)CIN * 9;
        for (int ci = 0; ci < CIN; ++ci) {
            const u16* Sr = S + ci * H2 * W2;
            float wa[9], wb[9];
#pragma unroll
            for (int q = 0; q < 9; ++q) { wa[q] = w0[ci * 9 + q]; wb[q] = w1[ci * 9 + q]; }
#pragma unroll
            for (int ky = 0; ky < 3; ++ky) {
                int yy = y + ky - 1;
                if (yy < 0 || yy >= H2) continue;
                float seg[10];
#pragma unroll
                for (int dx = 0; dx < 10; ++dx) {
                    int xx = x0p + dx - 1;
                    seg[dx] = (xx >= 0 && xx < W2) ? b2f(Sr[yy * W2 + xx]) : 0.f;
                }
#pragma unroll
                for (int d = 0; d < 8; ++d) {
                    acc0[d] = fmaf(seg[d],     wa[ky * 3 + 0], acc0[d]);
                    acc0[d] = fmaf(seg[d + 1], wa[ky * 3 + 1], acc0[d]);
                    acc0[d] = fmaf(seg[d + 2], wa[ky * 3 + 2], acc0[d]);
                    acc1[d] = fmaf(seg[d],     wb[ky * 3 + 0], acc1[d]);
                    acc1[d] = fmaf(seg[d + 1], wb[ky * 3 + 1], acc1[d]);
                    acc1[d] = fmaf(seg[d + 2], wb[ky * 3 + 2], acc1[d]);
                }
            }
        }
        u16* op0 = out + (((size_t)(n * CO + co0) * H2) + y) * W2 + x0p;
        u16* op1 = op0 + (size_t)H2 * W2;
#pragma unroll
        for (int d = 0; d < 8; ++d) { op0[d] = f2b(acc0[d]); op1[d] = f2b(acc1[d]); }
    }
}

// ======================================================================
__global__ __launch_bounds__(256) void up_conv6(
    const u16* __restrict__ c5, const float* __restrict__ w, const float* __restrict__ bias,
    u16* __restrict__ sl)
{
    __shared__ u16 S[40960];
    const int tid = threadIdx.x;
    const int n = blockIdx.x >> 3;
    const int band = blockIdx.x & 7;
    const int r0 = band * 8;
    const u16* ip = c5 + (size_t)n * 64 * 1024;

    for (int i = tid; i < 40960; i += 256) {
        int x2 = i & 63; int ry = (i >> 6) % 10; int ci = i / 640;
        int yy = r0 - 1 + ry;
        float v = 0.f;
        if (yy >= 0 && yy < 64) {
            int y0 = (yy - 1) >> 1; float fy = (yy & 1) ? 0.25f : 0.75f;
            int x0 = (x2 - 1) >> 1; float fx = (x2 & 1) ? 0.25f : 0.75f;
            int y0c = y0 < 0 ? 0 : y0, y1c = y0 + 1 > 31 ? 31 : y0 + 1;
            int x0c = x0 < 0 ? 0 : x0, x1c = x0 + 1 > 31 ? 31 : x0 + 1;
            const u16* b = ip + ci * 1024;
            float v00 = b2f(b[y0c * 32 + x0c]), v01 = b2f(b[y0c * 32 + x1c]);
            float v10 = b2f(b[y1c * 32 + x0c]), v11 = b2f(b[y1c * 32 + x1c]);
            v = fmaxf((1.f - fy) * ((1.f - fx) * v00 + fx * v01)
                      +      fy  * ((1.f - fx) * v10 + fx * v11), 0.f);
        }
        S[i] = f2b(v);
    }
    __syncthreads();

    for (int u = tid; u < 128; u += 256) {
        int x0p = (u & 7) * 8;
        int yr  = (u >> 3) & 7;
        int co  = u >> 6;
        int y = r0 + yr;
        float acc[8];
        float bb = bias[co];
#pragma unroll
        for (int d = 0; d < 8; ++d) acc[d] = bb;
        const float* wp = w + (size_t)co * 64 * 9;
        for (int ci = 0; ci < 64; ++ci) {
            const u16* Sr = S + ci * 640;
            float wk[9];
#pragma unroll
            for (int q = 0; q < 9; ++q) wk[q] = wp[ci * 9 + q];
#pragma unroll
            for (int ky = 0; ky < 3; ++ky) {
                int ry = yr + ky;
                float seg[10];
#pragma unroll
                for (int dx = 0; dx < 10; ++dx) {
                    int xx = x0p + dx - 1;
                    seg[dx] = (xx >= 0 && xx < 64) ? b2f(Sr[ry * 64 + xx]) : 0.f;
                }
#pragma unroll
                for (int d = 0; d < 8; ++d) {
                    acc[d] = fmaf(seg[d],     wk[ky * 3 + 0], acc[d]);
                    acc[d] = fmaf(seg[d + 1], wk[ky * 3 + 1], acc[d]);
                    acc[d] = fmaf(seg[d + 2], wk[ky * 3 + 2], acc[d]);
                }
            }
        }
        u16* op = sl + (size_t)(n * 2 + co) * 4096 + y * 64 + x0p;
#pragma unroll
        for (int d = 0; d < 8; ++d) op[d] = f2b(acc[d]);
    }
}

// ======================================================================
// softmax over 4096 logits -> FLOAT32 output
// ======================================================================
__global__ __launch_bounds__(256) void softmax_spatial(const u16* __restrict__ sl, float* __restrict__ out)
{
    __shared__ float red[256];
    const int b = blockIdx.x;
    const u16* src = sl + (size_t)b * 4096;
    float* dst = out + (size_t)b * 4096;
    const int tid = threadIdx.x;
    float m = -INFINITY;
    for (int i = tid; i < 4096; i += 256) m = fmaxf(m, b2f(src[i]));
    red[tid] = m; __syncthreads();
    for (int s = 128; s > 0; s >>= 1) { if (tid < s) red[tid] = fmaxf(red[tid], red[tid + s]); __syncthreads(); }
    m = red[0]; __syncthreads();
    float sum = 0.f;
    for (int i = tid; i < 4096; i += 256) sum += expf(b2f(src[i]) - m);
    red[tid] = sum; __syncthreads();
    for (int s = 128; s > 0; s >>= 1) { if (tid < s) red[tid] += red[tid + s]; __syncthreads(); }
    float inv = 1.f / red[0];
    for (int i = tid; i < 4096; i += 256) dst[i] = expf(b2f(src[i]) - m) * inv;
}

// ======================================================================
extern "C" void kernel_launch(void* const* d_in, const int* in_sizes, int n_in,
                              void* d_out, int out_size, void* d_ws, size_t ws_size,
                              hipStream_t stream)
{
    const float* G     = (const float*)d_in[0];
    const float* X     = (const float*)d_in[1];
    const int*   avail = (const int*)d_in[2];
    const float* lh    = (const float*)d_in[3];
    const float* pa    = (const float*)d_in[4];
    const int*   relf  = (const int*)d_in[5];
    const float* We  = (const float*)d_in[6];   const float* be  = (const float*)d_in[7];
    const float* W1  = (const float*)d_in[8];   const float* b1  = (const float*)d_in[9];
    const float* W2  = (const float*)d_in[10];  const float* b2  = (const float*)d_in[11];
    const float* W3  = (const float*)d_in[12];  const float* b3  = (const float*)d_in[13];
    const float* Wle = (const float*)d_in[14];  const float* ble = (const float*)d_in[15];
    const float* Wih = (const float*)d_in[16];  const float* Whh = (const float*)d_in[17];
    const float* bih = (const float*)d_in[18];  const float* bhh = (const float*)d_in[19];
    const float* Wa  = (const float*)d_in[20];  const float* ba  = (const float*)d_in[21];
    const float* Wv  = (const float*)d_in[22];  const float* bv  = (const float*)d_in[23];
    const float* Wt1 = (const float*)d_in[24];  const float* bt1 = (const float*)d_in[25];
    const float* Wc2 = (const float*)d_in[26];  const float* bc2 = (const float*)d_in[27];
    const float* Wc3 = (const float*)d_in[28];  const float* bc3 = (const float*)d_in[29];
    const float* Wc4 = (const float*)d_in[30];  const float* bc4 = (const float*)d_in[31];
    const float* Wc5 = (const float*)d_in[32];  const float* bc5 = (const float*)d_in[33];
    const float* Wc6 = (const float*)d_in[34];  const float* bc6 = (const float*)d_in[35];

    char* ws = (char*)d_ws;
    float* goaAll = (float*)(ws + WS_GOA);
    float* hbuf   = (float*)(ws + WS_HBUF);
    float* cbuf   = (float*)(ws + WS_CBUF);
    float* hout   = (float*)(ws + WS_HOUT);
    float* glo    = (float*)(ws + WS_GLO);
    float* wihT   = (float*)(ws + WS_WIHT);
    float* whhT   = (float*)(ws + WS_WHHT);
    float* bsum   = (float*)(ws + WS_BSUM);
    u16*   c2     = (u16*)(ws + WS_C2);
    u16*   c3     = (u16*)(ws + WS_C3);
    u16*   c4     = (u16*)(ws + WS_C4);
    u16*   c5     = (u16*)(ws + WS_C5);
    u16*   sl     = (u16*)(ws + WS_SL);
    float* out    = (float*)d_out;     // OUTPUT IS FLOAT32

    wtrans<<<1024, 256, 0, stream>>>(Wih, Whh, bih, bhh, wihT, whhT, bsum);
    gcn_kernel<<<2048, 512, 0, stream>>>(G, X, pa, We, be, W1, b1, W2, b2, W3, b3, goaAll);
    lstm_all<<<64, 256, 0, stream>>>(goaAll, Wle, ble, wihT, whhT, bsum, relf, lh,
                                     hbuf, cbuf, hout);
    heads<<<64, 256, 0, stream>>>(goaAll, hout, hbuf, cbuf, Wa, ba, Wv, bv, avail, glo, out);
    dec12<<<64, 256, 0, stream>>>(glo, Wt1, bt1, Wc2, bc2, c2);
    up_conv<<<512, 256, 0, stream>>>(c2, Wc3, bc3, c3, 128, 64, 4, 4, 8);
    up_conv<<<512, 256, 0, stream>>>(c3, Wc4, bc4, c4, 64, 64, 8, 8, 8);
    up_conv<<<512, 256, 0, stream>>>(c4, Wc5, bc5, c5, 64, 64, 16, 16, 8);
    up_conv6<<<512, 256, 0, stream>>>(c5, Wc6, bc6, sl);
    softmax_spatial<<<128, 256, 0, stream>>>(sl, out + OUT_SPATIAL);
}

// Round 6
// 4262.806 us; speedup vs baseline: 2.2180x; 2.2180x over previous
//
#include <hip/hip_runtime.h>
#include <math.h>

typedef unsigned short u16;
typedef unsigned int u32;

typedef __attribute__((ext_vector_type(8))) short bf16x8;
typedef __attribute__((ext_vector_type(4))) float f32x4;

// ---------- bf16 helpers (intermediates only; I/O is f32) ----------
__device__ __forceinline__ float b2f(u16 u) {
    union { u32 ui; float f; } v; v.ui = ((u32)u) << 16; return v.f;
}
__device__ __forceinline__ u16 f2b(float f) {
    union { float f; u32 ui; } v; v.f = f;
    u32 x = v.ui;
    u32 r = (x + 0x7fffu + ((x >> 16) & 1u)) >> 16;
    return (u16)r;
}
__device__ __forceinline__ float sigf(float x) { return 1.0f / (1.0f + expf(-x)); }

// ---------- problem constants ----------
#define GNODES 128
#define EMBD   256
#define NB     64
#define TS     32
#define GOA    268
#define GLO    524

// output layout (f32 elements)
#define OUT_SPATIAL 0
#define OUT_NS      524288
#define OUT_V       524800
#define OUT_H       524864

// workspace byte offsets
#define WS_GOA   ((size_t)0)
#define WS_HBUF  ((size_t)2195456)
#define WS_CBUF  ((size_t)2260992)
#define WS_HOUT  ((size_t)2326528)
#define WS_GLO   ((size_t)2392064)
#define WS_WIHT  ((size_t)2526208)
#define WS_WHHT  ((size_t)3574784)
#define WS_BSUM  ((size_t)4623360)
#define WS_C2    ((size_t)4627456)
#define WS_C3    ((size_t)4889600)
#define WS_C4    ((size_t)5413888)
#define WS_C5    ((size_t)7511040)
#define WS_SL    ((size_t)15899648)
#define WS_WET   ((size_t)16948224)   // 256*64 bf16 = 32768
#define WS_W1T   ((size_t)16980992)   // 256*256 bf16 = 131072
#define WS_W2T   ((size_t)17112064)
#define WS_W3T   ((size_t)17243136)   // end 17,374,208

// LDS strides (elements), multiples of 8 for 16B-aligned ds_read_b128
#define SA_S 264
#define TT_S 136
#define XS_S 72

// ======================================================================
// weight prep: transpose + bf16-cast GCN weights (n-major, k-contiguous)
// ======================================================================
__global__ void wprep(const float* __restrict__ We, const float* __restrict__ W1,
                      const float* __restrict__ W2, const float* __restrict__ W3,
                      u16* __restrict__ WeT, u16* __restrict__ W1T,
                      u16* __restrict__ W2T, u16* __restrict__ W3T)
{
    int idx = blockIdx.x * 256 + threadIdx.x;   // 65536 threads
    if (idx < 16384) {
        int k = idx >> 8, nn = idx & 255;       // We[k][n], k<64
        WeT[nn * 64 + k] = f2b(We[idx]);
    }
    {
        int k = idx >> 8, nn = idx & 255;       // W[k][n], 256x256
        W1T[nn * 256 + k] = f2b(W1[idx]);
        W2T[nn * 256 + k] = f2b(W2[idx]);
        W3T[nn * 256 + k] = f2b(W3[idx]);
    }
}

// ======================================================================
// GCN via MFMA. One block per (n,t) item, 512 threads = 8 waves.
// GEMM1: T = act @ W + b, stored transposed Tt[feat][node] in LDS.
// GEMM2 (A_agg symmetric): H^T = Tt @ A_agg, tanh, -> Sa[node][feat].
// A_agg B-fragments built once per item from G + dis, kept in VGPRs.
// ======================================================================
__global__ __launch_bounds__(512) void gcn_mfma(
    const float* __restrict__ G, const float* __restrict__ X, const float* __restrict__ pa,
    const u16* __restrict__ WeT, const float* __restrict__ be,
    const u16* __restrict__ W1T, const float* __restrict__ b1,
    const u16* __restrict__ W2T, const float* __restrict__ b2,
    const u16* __restrict__ W3T, const float* __restrict__ b3,
    float* __restrict__ goaAll)
{
    __shared__ u16 Sa[128 * SA_S];   // 67,584 B
    __shared__ u16 Tt[256 * TT_S];   // 69,632 B (also X staging)
    __shared__ float dis[GNODES];

    const int item = blockIdx.x;
    const int tid  = threadIdx.x;
    const int wv   = tid >> 6;          // wave 0..7
    const int lane = tid & 63;
    const int l16  = lane & 15;
    const int quad = lane >> 4;         // 0..3
    const float* Gp = G + (size_t)item * GNODES * GNODES;
    const float* Xp = X + (size_t)item * GNODES * 64;

    // stage X (f32->bf16) into Tt region at stride XS_S
    for (int idx = tid; idx < 128 * 64; idx += 512) {
        int m = idx >> 6, k = idx & 63;
        Tt[m * XS_S + k] = f2b(Xp[idx]);
    }
    if (tid < GNODES) {
        const float4* gr = (const float4*)(Gp + tid * GNODES);
        float s = 0.f;
        for (int k = 0; k < 32; ++k) { float4 g = gr[k]; s += g.x + g.y + g.z + g.w; }
        dis[tid] = 1.0f / sqrtf(s + 1.0f);
    }
    __syncthreads();

    // A_agg B-frags: b[t][j] = Aagg[k=32t+8*quad+j][i=16*wv+l16]  (symmetry)
    bf16x8 bAgg[4];
    {
        const int i = wv * 16 + l16;
        const float di = dis[i];
        const float* gr = Gp + (size_t)i * GNODES;
#pragma unroll
        for (int t = 0; t < 4; ++t) {
            const int k0 = t * 32 + quad * 8;
            float4 ga = *(const float4*)(gr + k0);
            float4 gb = *(const float4*)(gr + k0 + 4);
            float vv[8] = {ga.x, ga.y, ga.z, ga.w, gb.x, gb.y, gb.z, gb.w};
            bf16x8 f;
#pragma unroll
            for (int j = 0; j < 8; ++j) {
                int k = k0 + j;
                float a = (vv[j] + (k == i ? 1.0f : 0.0f)) * di * dis[k];
                f[j] = (short)f2b(a);
            }
            bAgg[t] = f;
        }
    }

    // ---- emb = tanh(X @ We + be) -> Sa[node][feat] ----
    {
        bf16x8 a0 = *(const bf16x8*)(Tt + (16 * wv + l16) * XS_S + quad * 8);
        bf16x8 a1 = *(const bf16x8*)(Tt + (16 * wv + l16) * XS_S + 32 + quad * 8);
#pragma unroll
        for (int ct = 0; ct < 16; ++ct) {
            const int nf = ct * 16 + l16;
            bf16x8 wb0 = *(const bf16x8*)(WeT + nf * 64 + quad * 8);
            bf16x8 wb1 = *(const bf16x8*)(WeT + nf * 64 + 32 + quad * 8);
            float bb = be[nf];
            f32x4 acc = {bb, bb, bb, bb};
            acc = __builtin_amdgcn_mfma_f32_16x16x32_bf16(a0, wb0, acc, 0, 0, 0);
            acc = __builtin_amdgcn_mfma_f32_16x16x32_bf16(a1, wb1, acc, 0, 0, 0);
#pragma unroll
            for (int r = 0; r < 4; ++r) {
                int node = 16 * wv + quad * 4 + r;
                Sa[node * SA_S + nf] = f2b(tanhf(acc[r]));
            }
        }
    }
    __syncthreads();

    const u16* WTs[3]  = {W1T, W2T, W3T};
    const float* bss[3] = {b1, b2, b3};

    for (int l = 0; l < 3; ++l) {
        const u16* WT = WTs[l];
        const float* bias = bss[l];

        // ---- GEMM1: Tt[feat][node] = (Sa @ W + b)^T ----
        // wave owns feature col-tiles c = 2wv, 2wv+1; loops 8 node row-tiles
        bf16x8 bfr[2][8];
        float bb[2];
#pragma unroll
        for (int cc = 0; cc < 2; ++cc) {
            int nf = (2 * wv + cc) * 16 + l16;
            bb[cc] = bias[nf];
#pragma unroll
            for (int t = 0; t < 8; ++t)
                bfr[cc][t] = *(const bf16x8*)(WT + (size_t)nf * 256 + t * 32 + quad * 8);
        }
        for (int rt = 0; rt < 8; ++rt) {
            bf16x8 afr[8];
#pragma unroll
            for (int t = 0; t < 8; ++t)
                afr[t] = *(const bf16x8*)(Sa + (16 * rt + l16) * SA_S + t * 32 + quad * 8);
#pragma unroll
            for (int cc = 0; cc < 2; ++cc) {
                f32x4 acc = {bb[cc], bb[cc], bb[cc], bb[cc]};
#pragma unroll
                for (int t = 0; t < 8; ++t)
                    acc = __builtin_amdgcn_mfma_f32_16x16x32_bf16(afr[t], bfr[cc][t], acc, 0, 0, 0);
                int nf = (2 * wv + cc) * 16 + l16;
                u16 p0 = f2b(acc[0]), p1 = f2b(acc[1]), p2 = f2b(acc[2]), p3 = f2b(acc[3]);
                uint2 pk; pk.x = (u32)p0 | ((u32)p1 << 16); pk.y = (u32)p2 | ((u32)p3 << 16);
                *(uint2*)(Tt + (size_t)nf * TT_S + 16 * rt + quad * 4) = pk;
            }
        }
        __syncthreads();

        // ---- GEMM2': Sa[node][feat] = tanh(Tt @ Aagg)  (H^T layout flip) ----
        for (int ft = 0; ft < 16; ++ft) {
            bf16x8 afr[4];
#pragma unroll
            for (int t = 0; t < 4; ++t)
                afr[t] = *(const bf16x8*)(Tt + (16 * ft + l16) * TT_S + t * 32 + quad * 8);
            f32x4 acc = {0.f, 0.f, 0.f, 0.f};
#pragma unroll
            for (int t = 0; t < 4; ++t)
                acc = __builtin_amdgcn_mfma_f32_16x16x32_bf16(afr[t], bAgg[t], acc, 0, 0, 0);
            int i = wv * 16 + l16;   // node (C col)
            u16 p0 = f2b(tanhf(acc[0])), p1 = f2b(tanhf(acc[1]));
            u16 p2 = f2b(tanhf(acc[2])), p3 = f2b(tanhf(acc[3]));
            uint2 pk; pk.x = (u32)p0 | ((u32)p1 << 16); pk.y = (u32)p2 | ((u32)p3 << 16);
            *(uint2*)(Sa + (size_t)i * SA_S + 16 * ft + quad * 4) = pk;
        }
        __syncthreads();
    }

    // goa = [max over nodes of h3, prev_actions]
    const int nb = item >> 5, tt = item & 31;
    float* gdst = goaAll + ((size_t)tt * NB + nb) * GOA;
    if (tid < 256) {
        float m = -2.0f;
        for (int i = 0; i < GNODES; ++i) m = fmaxf(m, b2f(Sa[i * SA_S + tid]));
        gdst[tid] = m;
    } else if (tid < 268) {
        gdst[256 + (tid - 256)] = pa[(size_t)item * 12 + (tid - 256)];
    }
}

// ======================================================================
__global__ void wtrans(const float* __restrict__ Wih, const float* __restrict__ Whh,
                       const float* __restrict__ bih, const float* __restrict__ bhh,
                       float* __restrict__ wihT, float* __restrict__ whhT, float* __restrict__ bsum)
{
    int idx = blockIdx.x * 256 + threadIdx.x;
    int r = idx >> 8;
    int k = idx & 255;
    wihT[k * 1024 + r] = Wih[idx];
    whhT[k * 1024 + r] = Whh[idx];
    if (idx < 1024) bsum[idx] = bih[idx] + bhh[idx];
}

// ======================================================================
__global__ __launch_bounds__(256) void lstm_all(
    const float* __restrict__ goaAll, const float* __restrict__ Wle, const float* __restrict__ ble,
    const float* __restrict__ wihT, const float* __restrict__ whhT, const float* __restrict__ bsum,
    const int* __restrict__ relf, const float* __restrict__ lh,
    float* __restrict__ hbuf, float* __restrict__ cbuf, float* __restrict__ hout)
{
    __shared__ float gl[GOA];
    __shared__ float xv[256];
    __shared__ float hv[256];
    const int n = blockIdx.x, u = threadIdx.x;

    hv[u] = lh[n * 256 + u];
    float cpriv = lh[16384 + n * 256 + u];
    const float blev = ble[u];
    const float bs0 = bsum[u], bs1 = bsum[256 + u], bs2 = bsum[512 + u], bs3 = bsum[768 + u];

    for (int t = 0; t < TS; ++t) {
        const float* gsrc = goaAll + ((size_t)t * NB + n) * GOA;
        gl[u] = gsrc[u];
        if (u < 12) gl[256 + u] = gsrc[256 + u];
        __syncthreads();

        float acc = blev;
        for (int k = 0; k < GOA; ++k) acc = fmaf(gl[k], Wle[k * 256 + u], acc);
        xv[u] = tanhf(acc);
        __syncthreads();

        float a0 = bs0, a1 = bs1, a2 = bs2, a3 = bs3;
        for (int k = 0; k < 256; ++k) {
            float xk = xv[k], hk = hv[k];
            const float* wi = wihT + k * 1024 + u;
            const float* wh = whhT + k * 1024 + u;
            a0 = fmaf(xk, wi[0],   fmaf(hk, wh[0],   a0));
            a1 = fmaf(xk, wi[256], fmaf(hk, wh[256], a1));
            a2 = fmaf(xk, wi[512], fmaf(hk, wh[512], a2));
            a3 = fmaf(xk, wi[768], fmaf(hk, wh[768], a3));
        }
        float cn = sigf(a1) * cpriv + sigf(a0) * tanhf(a2);
        float hn = sigf(a3) * tanhf(cn);
        float kp = (relf[n * TS + t] != 0) ? 1.f : 0.f;
        if (t == TS - 1) {
            hout[n * 256 + u] = hn;
            hbuf[n * 256 + u] = hn * kp;
            cbuf[n * 256 + u] = cn * kp;
        }
        cpriv = cn * kp;
        __syncthreads();
        hv[u] = hn * kp;
        __syncthreads();
    }
}

// ======================================================================
__global__ __launch_bounds__(256) void heads(
    const float* __restrict__ goaAll, const float* __restrict__ hout,
    const float* __restrict__ hbuf, const float* __restrict__ cbuf,
    const float* __restrict__ Wa, const float* __restrict__ ba,
    const float* __restrict__ Wv, const float* __restrict__ bv,
    const int* __restrict__ avail, float* __restrict__ glo, float* __restrict__ out)
{
    __shared__ float gl[GLO];
    __shared__ float lg[8];
    const int n = blockIdx.x, tid = threadIdx.x;
    const float* gsrc = goaAll + ((size_t)31 * NB + n) * GOA;
    gl[tid] = hout[n * 256 + tid];
    gl[256 + tid] = gsrc[tid];
    if (tid < 12) gl[512 + tid] = gsrc[256 + tid];
    __syncthreads();

    glo[n * GLO + tid]       = gl[tid];
    glo[n * GLO + 256 + tid] = gl[256 + tid];
    if (tid < 12) glo[n * GLO + 512 + tid] = gl[512 + tid];

    out[OUT_H + n * 256 + tid]         = hbuf[n * 256 + tid];
    out[OUT_H + 16384 + n * 256 + tid] = cbuf[n * 256 + tid];

    if (tid < 8) {
        float a = ba[tid];
        for (int k = 0; k < GLO; ++k) a = fmaf(gl[k], Wa[k * 8 + tid], a);
        lg[tid] = (avail[n * 8 + tid] == 0) ? -INFINITY : a;
    } else if (tid == 8) {
        float a = bv[0];
        for (int k = 0; k < GLO; ++k) a = fmaf(gl[k], Wv[k], a);
        out[OUT_V + n] = a;
    }
    __syncthreads();
    if (tid == 0) {
        float m = -INFINITY;
        for (int a = 0; a < 8; ++a) m = fmaxf(m, lg[a]);
        float e[8], s = 0.f;
        for (int a = 0; a < 8; ++a) { e[a] = expf(lg[a] - m); s += e[a]; }
        float inv = 1.f / s;
        for (int a = 0; a < 8; ++a) out[OUT_NS + n * 8 + a] = e[a] * inv;
    }
}

// ======================================================================
__global__ __launch_bounds__(256) void dec12(
    const float* __restrict__ glo, const float* __restrict__ Wt1, const float* __restrict__ bt1,
    const float* __restrict__ Wc2, const float* __restrict__ bc2, u16* __restrict__ c2)
{
    __shared__ float gl[GLO];
    __shared__ float s1[4096];
    const int n = blockIdx.x, tid = threadIdx.x;
    gl[tid] = glo[n * GLO + tid];
    gl[256 + tid] = glo[n * GLO + 256 + tid];
    if (tid < 12) gl[512 + tid] = glo[n * GLO + 512 + tid];
    __syncthreads();

    {
        const int f = tid;
        float acc[16];
        float bb = bt1[f];
#pragma unroll
        for (int p = 0; p < 16; ++p) acc[p] = bb;
        for (int c = 0; c < GLO; ++c) {
            float g = gl[c];
            const float* wp = Wt1 + ((size_t)c * 256 + f) * 16;
#pragma unroll
            for (int p = 0; p < 16; ++p) acc[p] = fmaf(g, wp[p], acc[p]);
        }
#pragma unroll
        for (int p = 0; p < 16; ++p) {
            float v = acc[p];
            s1[f * 16 + p] = v > 0.f ? v : 0.1f * v;
        }
    }
    __syncthreads();

    for (int u = tid; u < 2048; u += 256) {
        int p = u & 15; int x = p & 3; int y = p >> 2;
        int co = u >> 4;
        float acc = bc2[co];
        const float* wp = Wc2 + (size_t)co * 256 * 9;
        for (int ci = 0; ci < 256; ++ci) {
            const float* wc = wp + ci * 9;
            const float* sc = s1 + ci * 16;
#pragma unroll
            for (int ky = 0; ky < 3; ++ky) {
                int yy = y + ky - 1;
                if (yy < 0 || yy > 3) continue;
#pragma unroll
                for (int kx = 0; kx < 3; ++kx) {
                    int xx = x + kx - 1;
                    if (xx < 0 || xx > 3) continue;
                    acc = fmaf(sc[yy * 4 + xx], wc[ky * 3 + kx], acc);
                }
            }
        }
        c2[(size_t)(n * 128 + co) * 16 + p] = f2b(acc);
    }
}

// ======================================================================
__global__ __launch_bounds__(256) void up_conv(
    const u16* __restrict__ in, const float* __restrict__ w, const float* __restrict__ bias,
    u16* __restrict__ out, int CIN, int CO, int H, int W, int coTiles)
{
    __shared__ u16 S[65536];
    const int tid = threadIdx.x;
    const int n  = blockIdx.x / coTiles;
    const int ct = blockIdx.x % coTiles;
    const int H2 = 2 * H, W2 = 2 * W;
    const u16* ip = in + (size_t)n * CIN * H * W;

    const int tot = CIN * H2 * W2;
    for (int i = tid; i < tot; i += 256) {
        int x2 = i % W2; int y2 = (i / W2) % H2; int ci = i / (W2 * H2);
        int y0 = (y2 - 1) >> 1; float fy = (y2 & 1) ? 0.25f : 0.75f;
        int x0 = (x2 - 1) >> 1; float fx = (x2 & 1) ? 0.25f : 0.75f;
        int y0c = y0 < 0 ? 0 : y0, y1c = y0 + 1 > H - 1 ? H - 1 : y0 + 1;
        int x0c = x0 < 0 ? 0 : x0, x1c = x0 + 1 > W - 1 ? W - 1 : x0 + 1;
        const u16* b = ip + ci * H * W;
        float v00 = b2f(b[y0c * W + x0c]), v01 = b2f(b[y0c * W + x1c]);
        float v10 = b2f(b[y1c * W + x0c]), v11 = b2f(b[y1c * W + x1c]);
        float v = (1.f - fy) * ((1.f - fx) * v00 + fx * v01)
                +        fy  * ((1.f - fx) * v10 + fx * v11);
        S[i] = f2b(fmaxf(v, 0.f));
    }
    __syncthreads();

    const int xg = W2 >> 3;
    const int units = 4 * H2 * xg;
    for (int ugl = tid; ugl < units; ugl += 256) {
        int x0p = (ugl % xg) * 8;
        int y   = (ugl / xg) % H2;
        int cp  = ugl / (xg * H2);
        int co0 = ct * 8 + cp * 2;
        float acc0[8], acc1[8];
        float bb0 = bias[co0], bb1 = bias[co0 + 1];
#pragma unroll
        for (int d = 0; d < 8; ++d) { acc0[d] = bb0; acc1[d] = bb1; }
        const float* w0 = w + (size_t)co0 * CIN * 9;
        const float* w1 = w0 + (size_t)CIN * 9;
        for (int ci = 0; ci < CIN; ++ci) {
            const u16* Sr = S + ci * H2 * W2;
            float wa[9], wb[9];
#pragma unroll
            for (int q = 0; q < 9; ++q) { wa[q] = w0[ci * 9 + q]; wb[q] = w1[ci * 9 + q]; }
#pragma unroll
            for (int ky = 0; ky < 3; ++ky) {
                int yy = y + ky - 1;
                if (yy < 0 || yy >= H2) continue;
                float seg[10];
#pragma unroll
                for (int dx = 0; dx < 10; ++dx) {
                    int xx = x0p + dx - 1;
                    seg[dx] = (xx >= 0 && xx < W2) ? b2f(Sr[yy * W2 + xx]) : 0.f;
                }
#pragma unroll
                for (int d = 0; d < 8; ++d) {
                    acc0[d] = fmaf(seg[d],     wa[ky * 3 + 0], acc0[d]);
                    acc0[d] = fmaf(seg[d + 1], wa[ky * 3 + 1], acc0[d]);
                    acc0[d] = fmaf(seg[d + 2], wa[ky * 3 + 2], acc0[d]);
                    acc1[d] = fmaf(seg[d],     wb[ky * 3 + 0], acc1[d]);
                    acc1[d] = fmaf(seg[d + 1], wb[ky * 3 + 1], acc1[d]);
                    acc1[d] = fmaf(seg[d + 2], wb[ky * 3 + 2], acc1[d]);
                }
            }
        }
        u16* op0 = out + (((size_t)(n * CO + co0) * H2) + y) * W2 + x0p;
        u16* op1 = op0 + (size_t)H2 * W2;
#pragma unroll
        for (int d = 0; d < 8; ++d) { op0[d] = f2b(acc0[d]); op1[d] = f2b(acc1[d]); }
    }
}

// ======================================================================
__global__ __launch_bounds__(256) void up_conv6(
    const u16* __restrict__ c5, const float* __restrict__ w, const float* __restrict__ bias,
    u16* __restrict__ sl)
{
    __shared__ u16 S[40960];
    const int tid = threadIdx.x;
    const int n = blockIdx.x >> 3;
    const int band = blockIdx.x & 7;
    const int r0 = band * 8;
    const u16* ip = c5 + (size_t)n * 64 * 1024;

    for (int i = tid; i < 40960; i += 256) {
        int x2 = i & 63; int ry = (i >> 6) % 10; int ci = i / 640;
        int yy = r0 - 1 + ry;
        float v = 0.f;
        if (yy >= 0 && yy < 64) {
            int y0 = (yy - 1) >> 1; float fy = (yy & 1) ? 0.25f : 0.75f;
            int x0 = (x2 - 1) >> 1; float fx = (x2 & 1) ? 0.25f : 0.75f;
            int y0c = y0 < 0 ? 0 : y0, y1c = y0 + 1 > 31 ? 31 : y0 + 1;
            int x0c = x0 < 0 ? 0 : x0, x1c = x0 + 1 > 31 ? 31 : x0 + 1;
            const u16* b = ip + ci * 1024;
            float v00 = b2f(b[y0c * 32 + x0c]), v01 = b2f(b[y0c * 32 + x1c]);
            float v10 = b2f(b[y1c * 32 + x0c]), v11 = b2f(b[y1c * 32 + x1c]);
            v = fmaxf((1.f - fy) * ((1.f - fx) * v00 + fx * v01)
                      +      fy  * ((1.f - fx) * v10 + fx * v11), 0.f);
        }
        S[i] = f2b(v);
    }
    __syncthreads();

    for (int u = tid; u < 128; u += 256) {
        int x0p = (u & 7) * 8;
        int yr  = (u >> 3) & 7;
        int co  = u >> 6;
        int y = r0 + yr;
        float acc[8];
        float bb = bias[co];
#pragma unroll
        for (int d = 0; d < 8; ++d) acc[d] = bb;
        const float* wp = w + (size_t)co * 64 * 9;
        for (int ci = 0; ci < 64; ++ci) {
            const u16* Sr = S + ci * 640;
            float wk[9];
#pragma unroll
            for (int q = 0; q < 9; ++q) wk[q] = wp[ci * 9 + q];
#pragma unroll
            for (int ky = 0; ky < 3; ++ky) {
                int ry = yr + ky;
                float seg[10];
#pragma unroll
                for (int dx = 0; dx < 10; ++dx) {
                    int xx = x0p + dx - 1;
                    seg[dx] = (xx >= 0 && xx < 64) ? b2f(Sr[ry * 64 + xx]) : 0.f;
                }
#pragma unroll
                for (int d = 0; d < 8; ++d) {
                    acc[d] = fmaf(seg[d],     wk[ky * 3 + 0], acc[d]);
                    acc[d] = fmaf(seg[d + 1], wk[ky * 3 + 1], acc[d]);
                    acc[d] = fmaf(seg[d + 2], wk[ky * 3 + 2], acc[d]);
                }
            }
        }
        u16* op = sl + (size_t)(n * 2 + co) * 4096 + y * 64 + x0p;
#pragma unroll
        for (int d = 0; d < 8; ++d) op[d] = f2b(acc[d]);
    }
}

// ======================================================================
__global__ __launch_bounds__(256) void softmax_spatial(const u16* __restrict__ sl, float* __restrict__ out)
{
    __shared__ float red[256];
    const int b = blockIdx.x;
    const u16* src = sl + (size_t)b * 4096;
    float* dst = out + (size_t)b * 4096;
    const int tid = threadIdx.x;
    float m = -INFINITY;
    for (int i = tid; i < 4096; i += 256) m = fmaxf(m, b2f(src[i]));
    red[tid] = m; __syncthreads();
    for (int s = 128; s > 0; s >>= 1) { if (tid < s) red[tid] = fmaxf(red[tid], red[tid + s]); __syncthreads(); }
    m = red[0]; __syncthreads();
    float sum = 0.f;
    for (int i = tid; i < 4096; i += 256) sum += expf(b2f(src[i]) - m);
    red[tid] = sum; __syncthreads();
    for (int s = 128; s > 0; s >>= 1) { if (tid < s) red[tid] += red[tid + s]; __syncthreads(); }
    float inv = 1.f / red[0];
    for (int i = tid; i < 4096; i += 256) dst[i] = expf(b2f(src[i]) - m) * inv;
}

// ======================================================================
extern "C" void kernel_launch(void* const* d_in, const int* in_sizes, int n_in,
                              void* d_out, int out_size, void* d_ws, size_t ws_size,
                              hipStream_t stream)
{
    const float* G     = (const float*)d_in[0];
    const float* X     = (const float*)d_in[1];
    const int*   avail = (const int*)d_in[2];
    const float* lh    = (const float*)d_in[3];
    const float* pa    = (const float*)d_in[4];
    const int*   relf  = (const int*)d_in[5];
    const float* We  = (const float*)d_in[6];   const float* be  = (const float*)d_in[7];
    const float* W1  = (const float*)d_in[8];   const float* b1  = (const float*)d_in[9];
    const float* W2  = (const float*)d_in[10];  const float* b2  = (const float*)d_in[11];
    const float* W3  = (const float*)d_in[12];  const float* b3  = (const float*)d_in[13];
    const float* Wle = (const float*)d_in[14];  const float* ble = (const float*)d_in[15];
    const float* Wih = (const float*)d_in[16];  const float* Whh = (const float*)d_in[17];
    const float* bih = (const float*)d_in[18];  const float* bhh = (const float*)d_in[19];
    const float* Wa  = (const float*)d_in[20];  const float* ba  = (const float*)d_in[21];
    const float* Wv  = (const float*)d_in[22];  const float* bv  = (const float*)d_in[23];
    const float* Wt1 = (const float*)d_in[24];  const float* bt1 = (const float*)d_in[25];
    const float* Wc2 = (const float*)d_in[26];  const float* bc2 = (const float*)d_in[27];
    const float* Wc3 = (const float*)d_in[28];  const float* bc3 = (const float*)d_in[29];
    const float* Wc4 = (const float*)d_in[30];  const float* bc4 = (const float*)d_in[31];
    const float* Wc5 = (const float*)d_in[32];  const float* bc5 = (const float*)d_in[33];
    const float* Wc6 = (const float*)d_in[34];  const float* bc6 = (const float*)d_in[35];

    char* ws = (char*)d_ws;
    float* goaAll = (float*)(ws + WS_GOA);
    float* hbuf   = (float*)(ws + WS_HBUF);
    float* cbuf   = (float*)(ws + WS_CBUF);
    float* hout   = (float*)(ws + WS_HOUT);
    float* glo    = (float*)(ws + WS_GLO);
    float* wihT   = (float*)(ws + WS_WIHT);
    float* whhT   = (float*)(ws + WS_WHHT);
    float* bsum   = (float*)(ws + WS_BSUM);
    u16*   c2     = (u16*)(ws + WS_C2);
    u16*   c3     = (u16*)(ws + WS_C3);
    u16*   c4     = (u16*)(ws + WS_C4);
    u16*   c5     = (u16*)(ws + WS_C5);
    u16*   sl     = (u16*)(ws + WS_SL);
    u16*   WeT    = (u16*)(ws + WS_WET);
    u16*   W1T    = (u16*)(ws + WS_W1T);
    u16*   W2T    = (u16*)(ws + WS_W2T);
    u16*   W3T    = (u16*)(ws + WS_W3T);
    float* out    = (float*)d_out;     // OUTPUT IS FLOAT32

    wprep<<<256, 256, 0, stream>>>(We, W1, W2, W3, WeT, W1T, W2T, W3T);
    wtrans<<<1024, 256, 0, stream>>>(Wih, Whh, bih, bhh, wihT, whhT, bsum);
    gcn_mfma<<<2048, 512, 0, stream>>>(G, X, pa, WeT, be, W1T, b1, W2T, b2, W3T, b3, goaAll);
    lstm_all<<<64, 256, 0, stream>>>(goaAll, Wle, ble, wihT, whhT, bsum, relf, lh,
                                     hbuf, cbuf, hout);
    heads<<<64, 256, 0, stream>>>(goaAll, hout, hbuf, cbuf, Wa, ba, Wv, bv, avail, glo, out);
    dec12<<<64, 256, 0, stream>>>(glo, Wt1, bt1, Wc2, bc2, c2);
    up_conv<<<512, 256, 0, stream>>>(c2, Wc3, bc3, c3, 128, 64, 4, 4, 8);
    up_conv<<<512, 256, 0, stream>>>(c3, Wc4, bc4, c4, 64, 64, 8, 8, 8);
    up_conv<<<512, 256, 0, stream>>>(c4, Wc5, bc5, c5, 64, 64, 16, 16, 8);
    up_conv6<<<512, 256, 0, stream>>>(c5, Wc6, bc6, sl);
    softmax_spatial<<<128, 256, 0, stream>>>(sl, out + OUT_SPATIAL);
}

// Round 7
// 2472.240 us; speedup vs baseline: 3.8243x; 1.7243x over previous
//
#include <hip/hip_runtime.h>
#include <math.h>

typedef unsigned short u16;
typedef unsigned int u32;

typedef __attribute__((ext_vector_type(8))) short bf16x8;
typedef __attribute__((ext_vector_type(4))) float f32x4;

// ---------- bf16 helpers (intermediates only; I/O is f32) ----------
__device__ __forceinline__ float b2f(u16 u) {
    union { u32 ui; float f; } v; v.ui = ((u32)u) << 16; return v.f;
}
__device__ __forceinline__ u16 f2b(float f) {
    union { float f; u32 ui; } v; v.f = f;
    u32 x = v.ui;
    u32 r = (x + 0x7fffu + ((x >> 16) & 1u)) >> 16;
    return (u16)r;
}
__device__ __forceinline__ float sigf(float x) { return 1.0f / (1.0f + expf(-x)); }

// ---------- problem constants ----------
#define GNODES 128
#define EMBD   256
#define NB     64
#define TS     32
#define GOA    268
#define GLO    524

// output layout (f32 elements)
#define OUT_SPATIAL 0
#define OUT_NS      524288
#define OUT_V       524800
#define OUT_H       524864

// workspace byte offsets
#define WS_GOA   ((size_t)0)
#define WS_HBUF  ((size_t)2195456)
#define WS_CBUF  ((size_t)2260992)
#define WS_HOUT  ((size_t)2326528)
#define WS_GLO   ((size_t)2392064)
#define WS_WIHT  ((size_t)2526208)
#define WS_WHHT  ((size_t)3574784)
#define WS_BSUM  ((size_t)4623360)
#define WS_C2    ((size_t)4627456)
#define WS_C3    ((size_t)4889600)
#define WS_C4    ((size_t)5413888)
#define WS_C5    ((size_t)7511040)
#define WS_SL    ((size_t)15899648)
#define WS_WET   ((size_t)16948224)   // 256*64 bf16
#define WS_W1T   ((size_t)16980992)   // 256*256 bf16
#define WS_W2T   ((size_t)17112064)
#define WS_W3T   ((size_t)17243136)
#define WS_GX    ((size_t)17374208)   // 2048*1024 f32 = 8,388,608
#define WS_S1F   ((size_t)25762816)   // 64*4096 f32 = 1,048,576 -> end 26,811,392

// LDS strides (elements)
#define SA_S 264
#define TT_S 136
#define XS_S 72

// ======================================================================
// weight prep: transpose + bf16-cast GCN weights
// ======================================================================
__global__ void wprep(const float* __restrict__ We, const float* __restrict__ W1,
                      const float* __restrict__ W2, const float* __restrict__ W3,
                      u16* __restrict__ WeT, u16* __restrict__ W1T,
                      u16* __restrict__ W2T, u16* __restrict__ W3T)
{
    int idx = blockIdx.x * 256 + threadIdx.x;
    if (idx < 16384) {
        int k = idx >> 8, nn = idx & 255;
        WeT[nn * 64 + k] = f2b(We[idx]);
    }
    {
        int k = idx >> 8, nn = idx & 255;
        W1T[nn * 256 + k] = f2b(W1[idx]);
        W2T[nn * 256 + k] = f2b(W2[idx]);
        W3T[nn * 256 + k] = f2b(W3[idx]);
    }
}

// ======================================================================
// GCN via MFMA (unchanged from round 6)
// ======================================================================
__global__ __launch_bounds__(512) void gcn_mfma(
    const float* __restrict__ G, const float* __restrict__ X, const float* __restrict__ pa,
    const u16* __restrict__ WeT, const float* __restrict__ be,
    const u16* __restrict__ W1T, const float* __restrict__ b1,
    const u16* __restrict__ W2T, const float* __restrict__ b2,
    const u16* __restrict__ W3T, const float* __restrict__ b3,
    float* __restrict__ goaAll)
{
    __shared__ u16 Sa[128 * SA_S];
    __shared__ u16 Tt[256 * TT_S];
    __shared__ float dis[GNODES];

    const int item = blockIdx.x;
    const int tid  = threadIdx.x;
    const int wv   = tid >> 6;
    const int lane = tid & 63;
    const int l16  = lane & 15;
    const int quad = lane >> 4;
    const float* Gp = G + (size_t)item * GNODES * GNODES;
    const float* Xp = X + (size_t)item * GNODES * 64;

    for (int idx = tid; idx < 128 * 64; idx += 512) {
        int m = idx >> 6, k = idx & 63;
        Tt[m * XS_S + k] = f2b(Xp[idx]);
    }
    if (tid < GNODES) {
        const float4* gr = (const float4*)(Gp + tid * GNODES);
        float s = 0.f;
        for (int k = 0; k < 32; ++k) { float4 g = gr[k]; s += g.x + g.y + g.z + g.w; }
        dis[tid] = 1.0f / sqrtf(s + 1.0f);
    }
    __syncthreads();

    bf16x8 bAgg[4];
    {
        const int i = wv * 16 + l16;
        const float di = dis[i];
        const float* gr = Gp + (size_t)i * GNODES;
#pragma unroll
        for (int t = 0; t < 4; ++t) {
            const int k0 = t * 32 + quad * 8;
            float4 ga = *(const float4*)(gr + k0);
            float4 gb = *(const float4*)(gr + k0 + 4);
            float vv[8] = {ga.x, ga.y, ga.z, ga.w, gb.x, gb.y, gb.z, gb.w};
            bf16x8 f;
#pragma unroll
            for (int j = 0; j < 8; ++j) {
                int k = k0 + j;
                float a = (vv[j] + (k == i ? 1.0f : 0.0f)) * di * dis[k];
                f[j] = (short)f2b(a);
            }
            bAgg[t] = f;
        }
    }

    {
        bf16x8 a0 = *(const bf16x8*)(Tt + (16 * wv + l16) * XS_S + quad * 8);
        bf16x8 a1 = *(const bf16x8*)(Tt + (16 * wv + l16) * XS_S + 32 + quad * 8);
#pragma unroll
        for (int ct = 0; ct < 16; ++ct) {
            const int nf = ct * 16 + l16;
            bf16x8 wb0 = *(const bf16x8*)(WeT + nf * 64 + quad * 8);
            bf16x8 wb1 = *(const bf16x8*)(WeT + nf * 64 + 32 + quad * 8);
            float bb = be[nf];
            f32x4 acc = {bb, bb, bb, bb};
            acc = __builtin_amdgcn_mfma_f32_16x16x32_bf16(a0, wb0, acc, 0, 0, 0);
            acc = __builtin_amdgcn_mfma_f32_16x16x32_bf16(a1, wb1, acc, 0, 0, 0);
#pragma unroll
            for (int r = 0; r < 4; ++r) {
                int node = 16 * wv + quad * 4 + r;
                Sa[node * SA_S + nf] = f2b(tanhf(acc[r]));
            }
        }
    }
    __syncthreads();

    const u16* WTs[3]  = {W1T, W2T, W3T};
    const float* bss[3] = {b1, b2, b3};

    for (int l = 0; l < 3; ++l) {
        const u16* WT = WTs[l];
        const float* bias = bss[l];

        bf16x8 bfr[2][8];
        float bb[2];
#pragma unroll
        for (int cc = 0; cc < 2; ++cc) {
            int nf = (2 * wv + cc) * 16 + l16;
            bb[cc] = bias[nf];
#pragma unroll
            for (int t = 0; t < 8; ++t)
                bfr[cc][t] = *(const bf16x8*)(WT + (size_t)nf * 256 + t * 32 + quad * 8);
        }
        for (int rt = 0; rt < 8; ++rt) {
            bf16x8 afr[8];
#pragma unroll
            for (int t = 0; t < 8; ++t)
                afr[t] = *(const bf16x8*)(Sa + (16 * rt + l16) * SA_S + t * 32 + quad * 8);
#pragma unroll
            for (int cc = 0; cc < 2; ++cc) {
                f32x4 acc = {bb[cc], bb[cc], bb[cc], bb[cc]};
#pragma unroll
                for (int t = 0; t < 8; ++t)
                    acc = __builtin_amdgcn_mfma_f32_16x16x32_bf16(afr[t], bfr[cc][t], acc, 0, 0, 0);
                int nf = (2 * wv + cc) * 16 + l16;
                u16 p0 = f2b(acc[0]), p1 = f2b(acc[1]), p2 = f2b(acc[2]), p3 = f2b(acc[3]);
                uint2 pk; pk.x = (u32)p0 | ((u32)p1 << 16); pk.y = (u32)p2 | ((u32)p3 << 16);
                *(uint2*)(Tt + (size_t)nf * TT_S + 16 * rt + quad * 4) = pk;
            }
        }
        __syncthreads();

        for (int ft = 0; ft < 16; ++ft) {
            bf16x8 afr[4];
#pragma unroll
            for (int t = 0; t < 4; ++t)
                afr[t] = *(const bf16x8*)(Tt + (16 * ft + l16) * TT_S + t * 32 + quad * 8);
            f32x4 acc = {0.f, 0.f, 0.f, 0.f};
#pragma unroll
            for (int t = 0; t < 4; ++t)
                acc = __builtin_amdgcn_mfma_f32_16x16x32_bf16(afr[t], bAgg[t], acc, 0, 0, 0);
            int i = wv * 16 + l16;
            u16 p0 = f2b(tanhf(acc[0])), p1 = f2b(tanhf(acc[1]));
            u16 p2 = f2b(tanhf(acc[2])), p3 = f2b(tanhf(acc[3]));
            uint2 pk; pk.x = (u32)p0 | ((u32)p1 << 16); pk.y = (u32)p2 | ((u32)p3 << 16);
            *(uint2*)(Sa + (size_t)i * SA_S + 16 * ft + quad * 4) = pk;
        }
        __syncthreads();
    }

    const int nb = item >> 5, tt = item & 31;
    float* gdst = goaAll + ((size_t)tt * NB + nb) * GOA;
    if (tid < 256) {
        float m = -2.0f;
        for (int i = 0; i < GNODES; ++i) m = fmaxf(m, b2f(Sa[i * SA_S + tid]));
        gdst[tid] = m;
    } else if (tid < 268) {
        gdst[256 + (tid - 256)] = pa[(size_t)item * 12 + (tid - 256)];
    }
}

// ======================================================================
__global__ void wtrans(const float* __restrict__ Wih, const float* __restrict__ Whh,
                       const float* __restrict__ bih, const float* __restrict__ bhh,
                       float* __restrict__ wihT, float* __restrict__ whhT, float* __restrict__ bsum)
{
    int idx = blockIdx.x * 256 + threadIdx.x;
    int r = idx >> 8;
    int k = idx & 255;
    wihT[k * 1024 + r] = Wih[idx];
    whhT[k * 1024 + r] = Whh[idx];
    if (idx < 1024) bsum[idx] = bih[idx] + bhh[idx];
}

// ======================================================================
// lstm_pre: parallel over all (t,n). xin = tanh(goa@Wle+ble) then
// gatesX = bsum + xin @ WihT. 2048 blocks x 256 threads.
// ======================================================================
__global__ __launch_bounds__(256) void lstm_pre(
    const float* __restrict__ goaAll, const float* __restrict__ Wle, const float* __restrict__ ble,
    const float* __restrict__ wihT, const float* __restrict__ bsum,
    float* __restrict__ gatesX)
{
    __shared__ float gl[GOA];
    __shared__ float xv[256];
    const int item = blockIdx.x;          // t*NB + n
    const int u = threadIdx.x;
    const float* gsrc = goaAll + (size_t)item * GOA;
    gl[u] = gsrc[u];
    if (u < 12) gl[256 + u] = gsrc[256 + u];
    __syncthreads();

    float acc = ble[u];
    for (int k = 0; k < GOA; ++k) acc = fmaf(gl[k], Wle[k * 256 + u], acc);
    xv[u] = tanhf(acc);
    __syncthreads();

    float* gdst = gatesX + (size_t)item * 1024;
#pragma unroll
    for (int g = 0; g < 4; ++g) {
        float a = bsum[g * 256 + u];
#pragma unroll 8
        for (int k = 0; k < 256; ++k)
            a = fmaf(xv[k], wihT[k * 1024 + g * 256 + u], a);
        gdst[g * 256 + u] = a;
    }
}

// ======================================================================
// lstm_seq: only the h-recurrence. 64 blocks x 1024 threads (16 waves).
// ======================================================================
__global__ __launch_bounds__(1024) void lstm_seq(
    const float* __restrict__ gatesX, const float* __restrict__ whhT,
    const int* __restrict__ relf, const float* __restrict__ lh,
    float* __restrict__ hbuf, float* __restrict__ cbuf, float* __restrict__ hout)
{
    __shared__ float hv[256];
    __shared__ float ga[1024];
    const int n = blockIdx.x, u = threadIdx.x;
    float cpriv = 0.f;
    if (u < 256) { hv[u] = lh[n * 256 + u]; cpriv = lh[16384 + n * 256 + u]; }
    __syncthreads();

    for (int t = 0; t < TS; ++t) {
        float a = gatesX[((size_t)t * NB + n) * 1024 + u];
        const float* wh = whhT + u;
#pragma unroll 8
        for (int k = 0; k < 256; ++k)
            a = fmaf(hv[k], wh[k * 1024], a);
        ga[u] = a;
        __syncthreads();
        if (u < 256) {
            float ai = ga[u], af = ga[256 + u], ag = ga[512 + u], ao = ga[768 + u];
            float cn = sigf(af) * cpriv + sigf(ai) * tanhf(ag);
            float hn = sigf(ao) * tanhf(cn);
            float kp = (relf[n * TS + t] != 0) ? 1.f : 0.f;
            if (t == TS - 1) {
                hout[n * 256 + u] = hn;
                hbuf[n * 256 + u] = hn * kp;
                cbuf[n * 256 + u] = cn * kp;
            }
            cpriv = cn * kp;
            hv[u] = hn * kp;
        }
        __syncthreads();
    }
}

// ======================================================================
__global__ __launch_bounds__(256) void heads(
    const float* __restrict__ goaAll, const float* __restrict__ hout,
    const float* __restrict__ hbuf, const float* __restrict__ cbuf,
    const float* __restrict__ Wa, const float* __restrict__ ba,
    const float* __restrict__ Wv, const float* __restrict__ bv,
    const int* __restrict__ avail, float* __restrict__ glo, float* __restrict__ out)
{
    __shared__ float gl[GLO];
    __shared__ float lg[8];
    const int n = blockIdx.x, tid = threadIdx.x;
    const float* gsrc = goaAll + ((size_t)31 * NB + n) * GOA;
    gl[tid] = hout[n * 256 + tid];
    gl[256 + tid] = gsrc[tid];
    if (tid < 12) gl[512 + tid] = gsrc[256 + tid];
    __syncthreads();

    glo[n * GLO + tid]       = gl[tid];
    glo[n * GLO + 256 + tid] = gl[256 + tid];
    if (tid < 12) glo[n * GLO + 512 + tid] = gl[512 + tid];

    out[OUT_H + n * 256 + tid]         = hbuf[n * 256 + tid];
    out[OUT_H + 16384 + n * 256 + tid] = cbuf[n * 256 + tid];

    if (tid < 8) {
        float a = ba[tid];
        for (int k = 0; k < GLO; ++k) a = fmaf(gl[k], Wa[k * 8 + tid], a);
        lg[tid] = (avail[n * 8 + tid] == 0) ? -INFINITY : a;
    } else if (tid == 8) {
        float a = bv[0];
        for (int k = 0; k < GLO; ++k) a = fmaf(gl[k], Wv[k], a);
        out[OUT_V + n] = a;
    }
    __syncthreads();
    if (tid == 0) {
        float m = -INFINITY;
        for (int a = 0; a < 8; ++a) m = fmaxf(m, lg[a]);
        float e[8], s = 0.f;
        for (int a = 0; a < 8; ++a) { e[a] = expf(lg[a] - m); s += e[a]; }
        float inv = 1.f / s;
        for (int a = 0; a < 8; ++a) out[OUT_NS + n * 8 + a] = e[a] * inv;
    }
}

// ======================================================================
// deconv1_k: s1f[n][f][p] = leaky(glo[n] . Wt1[:,f,p] + bt1[f])
// 256 blocks (one per f) x 256 threads (64 n x 4 p-groups).
// ======================================================================
__global__ __launch_bounds__(256) void deconv1_k(
    const float* __restrict__ glo, const float* __restrict__ Wt1, const float* __restrict__ bt1,
    float* __restrict__ s1f)
{
    const int f = blockIdx.x;
    const int tid = threadIdx.x;
    const int n = tid >> 2, pp = tid & 3;
    float bb = bt1[f];
    float a0 = bb, a1 = bb, a2 = bb, a3 = bb;
    const float* gp = glo + n * GLO;
    for (int c = 0; c < GLO; ++c) {
        float g = gp[c];
        float4 w4 = *(const float4*)&Wt1[(((size_t)c * 256 + f) << 4) + pp * 4];
        a0 = fmaf(g, w4.x, a0);
        a1 = fmaf(g, w4.y, a1);
        a2 = fmaf(g, w4.z, a2);
        a3 = fmaf(g, w4.w, a3);
    }
    float* dst = s1f + (((size_t)n * 256 + f) << 4) + pp * 4;
    dst[0] = a0 > 0.f ? a0 : 0.1f * a0;
    dst[1] = a1 > 0.f ? a1 : 0.1f * a1;
    dst[2] = a2 > 0.f ? a2 : 0.1f * a2;
    dst[3] = a3 > 0.f ? a3 : 0.1f * a3;
}

// ======================================================================
// conv2_k: c2 = conv3x3(s1). 512 blocks = 64n x 8 co-tiles, 256 threads.
// s1 zero-padded to 6x6 per channel in LDS (no bounds divergence).
// ======================================================================
__global__ __launch_bounds__(256) void conv2_k(
    const float* __restrict__ s1f, const float* __restrict__ Wc2, const float* __restrict__ bc2,
    u16* __restrict__ c2)
{
    __shared__ float sp[256 * 36];   // 36,864 B
    const int n = blockIdx.x >> 3, cot = blockIdx.x & 7;
    const int tid = threadIdx.x;
    for (int i = tid; i < 256 * 36; i += 256) sp[i] = 0.f;
    __syncthreads();
    for (int i = tid; i < 4096; i += 256) {
        int ci = i >> 4, p = i & 15, y = p >> 2, x = p & 3;
        sp[ci * 36 + (y + 1) * 6 + (x + 1)] = s1f[((size_t)n * 256 + ci) * 16 + p];
    }
    __syncthreads();

    const int co = cot * 16 + (tid >> 4);
    const int p = tid & 15, y = p >> 2, x = p & 3;
    float acc = bc2[co];
    const float* wp = Wc2 + (size_t)co * 256 * 9;
    for (int ci = 0; ci < 256; ++ci) {
        const float* wc = wp + ci * 9;
        const float* s = sp + ci * 36 + y * 6 + x;
#pragma unroll
        for (int ky = 0; ky < 3; ++ky) {
#pragma unroll
            for (int kx = 0; kx < 3; ++kx)
                acc = fmaf(s[ky * 6 + kx], wc[ky * 3 + kx], acc);
        }
    }
    c2[((size_t)n * 128 + co) * 16 + p] = f2b(acc);
}

// ======================================================================
__global__ __launch_bounds__(256) void up_conv(
    const u16* __restrict__ in, const float* __restrict__ w, const float* __restrict__ bias,
    u16* __restrict__ out, int CIN, int CO, int H, int W, int coTiles)
{
    __shared__ u16 S[65536];
    const int tid = threadIdx.x;
    const int n  = blockIdx.x / coTiles;
    const int ct = blockIdx.x % coTiles;
    const int H2 = 2 * H, W2 = 2 * W;
    const u16* ip = in + (size_t)n * CIN * H * W;

    const int tot = CIN * H2 * W2;
    for (int i = tid; i < tot; i += 256) {
        int x2 = i % W2; int y2 = (i / W2) % H2; int ci = i / (W2 * H2);
        int y0 = (y2 - 1) >> 1; float fy = (y2 & 1) ? 0.25f : 0.75f;
        int x0 = (x2 - 1) >> 1; float fx = (x2 & 1) ? 0.25f : 0.75f;
        int y0c = y0 < 0 ? 0 : y0, y1c = y0 + 1 > H - 1 ? H - 1 : y0 + 1;
        int x0c = x0 < 0 ? 0 : x0, x1c = x0 + 1 > W - 1 ? W - 1 : x0 + 1;
        const u16* b = ip + ci * H * W;
        float v00 = b2f(b[y0c * W + x0c]), v01 = b2f(b[y0c * W + x1c]);
        float v10 = b2f(b[y1c * W + x0c]), v11 = b2f(b[y1c * W + x1c]);
        float v = (1.f - fy) * ((1.f - fx) * v00 + fx * v01)
                +        fy  * ((1.f - fx) * v10 + fx * v11);
        S[i] = f2b(fmaxf(v, 0.f));
    }
    __syncthreads();

    const int xg = W2 >> 3;
    const int units = 4 * H2 * xg;
    for (int ugl = tid; ugl < units; ugl += 256) {
        int x0p = (ugl % xg) * 8;
        int y   = (ugl / xg) % H2;
        int cp  = ugl / (xg * H2);
        int co0 = ct * 8 + cp * 2;
        float acc0[8], acc1[8];
        float bb0 = bias[co0], bb1 = bias[co0 + 1];
#pragma unroll
        for (int d = 0; d < 8; ++d) { acc0[d] = bb0; acc1[d] = bb1; }
        const float* w0 = w + (size_t)co0 * CIN * 9;
        const float* w1 = w0 + (size_t)CIN * 9;
        for (int ci = 0; ci < CIN; ++ci) {
            const u16* Sr = S + ci * H2 * W2;
            float wa[9], wb[9];
#pragma unroll
            for (int q = 0; q < 9; ++q) { wa[q] = w0[ci * 9 + q]; wb[q] = w1[ci * 9 + q]; }
#pragma unroll
            for (int ky = 0; ky < 3; ++ky) {
                int yy = y + ky - 1;
                if (yy < 0 || yy >= H2) continue;
                float seg[10];
#pragma unroll
                for (int dx = 0; dx < 10; ++dx) {
                    int xx = x0p + dx - 1;
                    seg[dx] = (xx >= 0 && xx < W2) ? b2f(Sr[yy * W2 + xx]) : 0.f;
                }
#pragma unroll
                for (int d = 0; d < 8; ++d) {
                    acc0[d] = fmaf(seg[d],     wa[ky * 3 + 0], acc0[d]);
                    acc0[d] = fmaf(seg[d + 1], wa[ky * 3 + 1], acc0[d]);
                    acc0[d] = fmaf(seg[d + 2], wa[ky * 3 + 2], acc0[d]);
                    acc1[d] = fmaf(seg[d],     wb[ky * 3 + 0], acc1[d]);
                    acc1[d] = fmaf(seg[d + 1], wb[ky * 3 + 1], acc1[d]);
                    acc1[d] = fmaf(seg[d + 2], wb[ky * 3 + 2], acc1[d]);
                }
            }
        }
        u16* op0 = out + (((size_t)(n * CO + co0) * H2) + y) * W2 + x0p;
        u16* op1 = op0 + (size_t)H2 * W2;
#pragma unroll
        for (int d = 0; d < 8; ++d) { op0[d] = f2b(acc0[d]); op1[d] = f2b(acc1[d]); }
    }
}

// ======================================================================
__global__ __launch_bounds__(256) void up_conv6(
    const u16* __restrict__ c5, const float* __restrict__ w, const float* __restrict__ bias,
    u16* __restrict__ sl)
{
    __shared__ u16 S[40960];
    const int tid = threadIdx.x;
    const int n = blockIdx.x >> 3;
    const int band = blockIdx.x & 7;
    const int r0 = band * 8;
    const u16* ip = c5 + (size_t)n * 64 * 1024;

    for (int i = tid; i < 40960; i += 256) {
        int x2 = i & 63; int ry = (i >> 6) % 10; int ci = i / 640;
        int yy = r0 - 1 + ry;
        float v = 0.f;
        if (yy >= 0 && yy < 64) {
            int y0 = (yy - 1) >> 1; float fy = (yy & 1) ? 0.25f : 0.75f;
            int x0 = (x2 - 1) >> 1; float fx = (x2 & 1) ? 0.25f : 0.75f;
            int y0c = y0 < 0 ? 0 : y0, y1c = y0 + 1 > 31 ? 31 : y0 + 1;
            int x0c = x0 < 0 ? 0 : x0, x1c = x0 + 1 > 31 ? 31 : x0 + 1;
            const u16* b = ip + ci * 1024;
            float v00 = b2f(b[y0c * 32 + x0c]), v01 = b2f(b[y0c * 32 + x1c]);
            float v10 = b2f(b[y1c * 32 + x0c]), v11 = b2f(b[y1c * 32 + x1c]);
            v = fmaxf((1.f - fy) * ((1.f - fx) * v00 + fx * v01)
                      +      fy  * ((1.f - fx) * v10 + fx * v11), 0.f);
        }
        S[i] = f2b(v);
    }
    __syncthreads();

    for (int u = tid; u < 128; u += 256) {
        int x0p = (u & 7) * 8;
        int yr  = (u >> 3) & 7;
        int co  = u >> 6;
        int y = r0 + yr;
        float acc[8];
        float bb = bias[co];
#pragma unroll
        for (int d = 0; d < 8; ++d) acc[d] = bb;
        const float* wp = w + (size_t)co * 64 * 9;
        for (int ci = 0; ci < 64; ++ci) {
            const u16* Sr = S + ci * 640;
            float wk[9];
#pragma unroll
            for (int q = 0; q < 9; ++q) wk[q] = wp[ci * 9 + q];
#pragma unroll
            for (int ky = 0; ky < 3; ++ky) {
                int ry = yr + ky;
                float seg[10];
#pragma unroll
                for (int dx = 0; dx < 10; ++dx) {
                    int xx = x0p + dx - 1;
                    seg[dx] = (xx >= 0 && xx < 64) ? b2f(Sr[ry * 64 + xx]) : 0.f;
                }
#pragma unroll
                for (int d = 0; d < 8; ++d) {
                    acc[d] = fmaf(seg[d],     wk[ky * 3 + 0], acc[d]);
                    acc[d] = fmaf(seg[d + 1], wk[ky * 3 + 1], acc[d]);
                    acc[d] = fmaf(seg[d + 2], wk[ky * 3 + 2], acc[d]);
                }
            }
        }
        u16* op = sl + (size_t)(n * 2 + co) * 4096 + y * 64 + x0p;
#pragma unroll
        for (int d = 0; d < 8; ++d) op[d] = f2b(acc[d]);
    }
}

// ======================================================================
__global__ __launch_bounds__(256) void softmax_spatial(const u16* __restrict__ sl, float* __restrict__ out)
{
    __shared__ float red[256];
    const int b = blockIdx.x;
    const u16* src = sl + (size_t)b * 4096;
    float* dst = out + (size_t)b * 4096;
    const int tid = threadIdx.x;
    float m = -INFINITY;
    for (int i = tid; i < 4096; i += 256) m = fmaxf(m, b2f(src[i]));
    red[tid] = m; __syncthreads();
    for (int s = 128; s > 0; s >>= 1) { if (tid < s) red[tid] = fmaxf(red[tid], red[tid + s]); __syncthreads(); }
    m = red[0]; __syncthreads();
    float sum = 0.f;
    for (int i = tid; i < 4096; i += 256) sum += expf(b2f(src[i]) - m);
    red[tid] = sum; __syncthreads();
    for (int s = 128; s > 0; s >>= 1) { if (tid < s) red[tid] += red[tid + s]; __syncthreads(); }
    float inv = 1.f / red[0];
    for (int i = tid; i < 4096; i += 256) dst[i] = expf(b2f(src[i]) - m) * inv;
}

// ======================================================================
extern "C" void kernel_launch(void* const* d_in, const int* in_sizes, int n_in,
                              void* d_out, int out_size, void* d_ws, size_t ws_size,
                              hipStream_t stream)
{
    const float* G     = (const float*)d_in[0];
    const float* X     = (const float*)d_in[1];
    const int*   avail = (const int*)d_in[2];
    const float* lh    = (const float*)d_in[3];
    const float* pa    = (const float*)d_in[4];
    const int*   relf  = (const int*)d_in[5];
    const float* We  = (const float*)d_in[6];   const float* be  = (const float*)d_in[7];
    const float* W1  = (const float*)d_in[8];   const float* b1  = (const float*)d_in[9];
    const float* W2  = (const float*)d_in[10];  const float* b2  = (const float*)d_in[11];
    const float* W3  = (const float*)d_in[12];  const float* b3  = (const float*)d_in[13];
    const float* Wle = (const float*)d_in[14];  const float* ble = (const float*)d_in[15];
    const float* Wih = (const float*)d_in[16];  const float* Whh = (const float*)d_in[17];
    const float* bih = (const float*)d_in[18];  const float* bhh = (const float*)d_in[19];
    const float* Wa  = (const float*)d_in[20];  const float* ba  = (const float*)d_in[21];
    const float* Wv  = (const float*)d_in[22];  const float* bv  = (const float*)d_in[23];
    const float* Wt1 = (const float*)d_in[24];  const float* bt1 = (const float*)d_in[25];
    const float* Wc2 = (const float*)d_in[26];  const float* bc2 = (const float*)d_in[27];
    const float* Wc3 = (const float*)d_in[28];  const float* bc3 = (const float*)d_in[29];
    const float* Wc4 = (const float*)d_in[30];  const float* bc4 = (const float*)d_in[31];
    const float* Wc5 = (const float*)d_in[32];  const float* bc5 = (const float*)d_in[33];
    const float* Wc6 = (const float*)d_in[34];  const float* bc6 = (const float*)d_in[35];

    char* ws = (char*)d_ws;
    float* goaAll = (float*)(ws + WS_GOA);
    float* hbuf   = (float*)(ws + WS_HBUF);
    float* cbuf   = (float*)(ws + WS_CBUF);
    float* hout   = (float*)(ws + WS_HOUT);
    float* glo    = (float*)(ws + WS_GLO);
    float* wihT   = (float*)(ws + WS_WIHT);
    float* whhT   = (float*)(ws + WS_WHHT);
    float* bsum   = (float*)(ws + WS_BSUM);
    u16*   c2     = (u16*)(ws + WS_C2);
    u16*   c3     = (u16*)(ws + WS_C3);
    u16*   c4     = (u16*)(ws + WS_C4);
    u16*   c5     = (u16*)(ws + WS_C5);
    u16*   sl     = (u16*)(ws + WS_SL);
    u16*   WeT    = (u16*)(ws + WS_WET);
    u16*   W1T    = (u16*)(ws + WS_W1T);
    u16*   W2T    = (u16*)(ws + WS_W2T);
    u16*   W3T    = (u16*)(ws + WS_W3T);
    float* gatesX = (float*)(ws + WS_GX);
    float* s1f    = (float*)(ws + WS_S1F);
    float* out    = (float*)d_out;     // OUTPUT IS FLOAT32

    wprep<<<256, 256, 0, stream>>>(We, W1, W2, W3, WeT, W1T, W2T, W3T);
    wtrans<<<1024, 256, 0, stream>>>(Wih, Whh, bih, bhh, wihT, whhT, bsum);
    gcn_mfma<<<2048, 512, 0, stream>>>(G, X, pa, WeT, be, W1T, b1, W2T, b2, W3T, b3, goaAll);
    lstm_pre<<<2048, 256, 0, stream>>>(goaAll, Wle, ble, wihT, bsum, gatesX);
    lstm_seq<<<64, 1024, 0, stream>>>(gatesX, whhT, relf, lh, hbuf, cbuf, hout);
    heads<<<64, 256, 0, stream>>>(goaAll, hout, hbuf, cbuf, Wa, ba, Wv, bv, avail, glo, out);
    deconv1_k<<<256, 256, 0, stream>>>(glo, Wt1, bt1, s1f);
    conv2_k<<<512, 256, 0, stream>>>(s1f, Wc2, bc2, c2);
    up_conv<<<512, 256, 0, stream>>>(c2, Wc3, bc3, c3, 128, 64, 4, 4, 8);
    up_conv<<<512, 256, 0, stream>>>(c3, Wc4, bc4, c4, 64, 64, 8, 8, 8);
    up_conv<<<512, 256, 0, stream>>>(c4, Wc5, bc5, c5, 64, 64, 16, 16, 8);
    up_conv6<<<512, 256, 0, stream>>>(c5, Wc6, bc6, sl);
    softmax_spatial<<<128, 256, 0, stream>>>(sl, out + OUT_SPATIAL);
}